// Round 17
// baseline (409.894 us; speedup 1.0000x reference)
//
#include <hip/hip_runtime.h>

#define EPS 1e-5f

// table float offsets
#define OFF_S1   0
#define OFF_T1   800
#define OFF_A    8992
#define OFF_C1   13088
#define OFF_BNJ  13217
#define OFF_BND  13367
#define OFF_BN1  13517
#define OFF_BNL1 14157
#define OFF_BNL2 14413
#define OFF_CUS  14928
#define OFF_TMT  16384      // [64t][128co] f32

// byte layout
#define WF_B     98304
#define POOL_B   458752
#define PART_B   (POOL_B + 26214400)
#define OFF_PART2 (PART_B/4)
#define WT_B     (PART_B + 6553600)
#define OFF_WT   (WT_B/4)
#define OFF_FB   (OFF_WT + 256*2624)

// WF ush offsets
#define WF_W1    0
#define WF_W1B   4096
#define WF_W2    8192
#define WF_W2B   16384
#define WF_W3    24576
#define WF_W3B   40960
#define WF_LW1   57344
#define WF_LW2   106496
#define WF_JW2H  139264
#define WF_JW2L  141312
#define WF_DW2H  143360
#define WF_DW2L  145408
#define WF_AH    147456
#define WF_AL    151552
#define WF_SPAH  155648
#define WF_SPAL  156448

#define HBS 152   // sHB row stride (ush): 76 dw -> 2-way bank aliasing (free)

typedef unsigned short ushortT;
typedef float  f32x4 __attribute__((ext_vector_type(4)));
typedef short  s16x8 __attribute__((ext_vector_type(8)));

struct P {
  const float *x,*bn_joint,*jw1,*jb1,*jw2,*jb2,*bn_dif,*dw1,*db1,*dw2,*db2,
    *tw1,*tb1,*tw2,*tb2,*sw1,*sb1,*sw2,*sb2,*g1w,*g1b,*g2w,*g2b,
    *c1w,*c1w1,*c1b1,*bnc1,*c2w,*c2w1,*c2b1,*bnc2,*c3w,*c3w1,*c3b1,*bnc3,
    *lw1,*lb1,*bnl1,*lw2,*lb2,*bnl2,*fcw,*fcb,*hww,*hwb,*pw,*pb,*ls;
  float *ws, *out;
  const ushortT* wf;
  ushortT *poolb;
};

__device__ inline void lfence(){ __threadfence_block(); }

__device__ inline unsigned bbits(float x){
  union{float f;unsigned u;} a; a.f = x;
  return ((a.u + 0x7fffu + ((a.u>>16)&1u))>>16) & 0xffffu;
}
__device__ inline ushortT f2b(float x){ return (ushortT)bbits(x); }
__device__ inline float b2f(ushortT b){
  union{unsigned u;float f;} a; a.u = ((unsigned)b)<<16; return a.f;
}
__device__ inline f32x4 mfma16(s16x8 a, s16x8 b, f32x4 c){
  return __builtin_amdgcn_mfma_f32_16x16x32_bf16(a, b, c, 0, 0, 0);
}

__device__ inline void bn_pre(const float* bn, int C, float* dst, int gt, int NT){
  for (int c = gt; c < C; c += NT){
    float g = bn[c], b = bn[C+c], m = bn[2*C+c], v = bn[3*C+c];
    float s = g * rsqrtf(v + EPS);
    dst[c] = s; dst[C+c] = b - m*s;
  }
}

__device__ inline void wb_fill(const float* src, ushortT* dst, int COUT, int CIN, int gt, int NT){
  int KS = CIN/32;
  int total = COUT*CIN;
  for (int d = gt; d < total; d += NT){
    int j = d & 7, l = (d>>3) & 63, rest = d >> 9;
    int kk = rest % KS, tile = rest / KS;
    int co = tile*16 + (l & 15);
    int k  = kk*32 + (l >> 4)*8 + j;
    dst[d] = f2b(src[(size_t)co*CIN + k]);
  }
}

__device__ inline void wb_fill_hl(const float* src, ushortT* dh, ushortT* dl, int COUT, int CIN, int gt, int NT){
  int KS = CIN/32;
  int total = COUT*CIN;
  for (int d = gt; d < total; d += NT){
    int j = d & 7, l = (d>>3) & 63, rest = d >> 9;
    int kk = rest % KS, tile = rest / KS;
    int co = tile*16 + (l & 15);
    int k  = kk*32 + (l >> 4)*8 + j;
    float v = src[(size_t)co*CIN + k];
    ushortT h = f2b(v);
    dh[d] = h; dl[d] = f2b(v - b2f(h));
  }
}

__global__ __launch_bounds__(256) void k_pre1(P p){
  int gt = blockIdx.x*256 + threadIdx.x, NT = gridDim.x*256;
  float* ws = p.ws;
  bn_pre(p.bn_joint, 75, ws+OFF_BNJ, gt, NT);
  bn_pre(p.bn_dif,   75, ws+OFF_BND, gt, NT);
  bn_pre(p.bnc1,     64, ws+OFF_BN1, gt, NT);
  bn_pre(p.bnc2,    128, ws+OFF_BN1+128, gt, NT);
  bn_pre(p.bnc3,    128, ws+OFF_BN1+384, gt, NT);
  bn_pre(p.bnl1,    128, ws+OFF_BNL1, gt, NT);
  bn_pre(p.bnl2,    256, ws+OFF_BNL2, gt, NT);
  for (int idx = gt; idx < 800; idx += NT){
    int v = idx >> 5, o2 = idx & 31;
    float acc = p.sb2[o2];
    for (int o = 0; o < 64; o++){
      float e = fmaxf(p.sw1[o*25+v] + p.sb1[o], 0.f);
      acc += p.sw2[o2*64+o] * e;
    }
    ws[OFF_S1+idx] = fmaxf(acc, 0.f);
  }
  for (int idx = gt; idx < 8192; idx += NT){
    int o = idx / 64, t = idx % 64;
    float acc = p.tb2[o];
    for (int o1 = 0; o1 < 64; o1++){
      float e = fmaxf(p.tw1[o1*64+t] + p.tb1[o1], 0.f);
      acc += p.tw2[o*64+o1] * e;
    }
    ws[OFF_T1+idx] = fmaxf(acc, 0.f);
  }
  for (int idx = gt; idx < 4096; idx += NT){
    int i = idx / 64, j = idx % 64;
    float acc = 0.f;
    for (int c = 0; c < 128; c++) acc += p.g1w[c*64+i] * p.g2w[c*64+j];
    ws[OFF_A+idx] = acc;
  }
  if (gt < 64){
    float a = 0.f; for (int c = 0; c < 128; c++) a += p.g1b[c]*p.g2w[c*64+gt];
    ws[OFF_C1+gt] = a;
  } else if (gt < 128){
    int j = gt - 64;
    float a = 0.f; for (int c = 0; c < 128; c++) a += p.g2b[c]*p.g1w[c*64+j];
    ws[OFF_C1+64+j] = a;
  } else if (gt == 128){
    float a = 0.f; for (int c = 0; c < 128; c++) a += p.g1b[c]*p.g2b[c];
    ws[OFF_C1+128] = a;
  }
}

__global__ __launch_bounds__(256) void k_pre2(P p){
  int gt = blockIdx.x*256 + threadIdx.x, NT = gridDim.x*256;
  float* ws = p.ws;
  ushortT* wf = (ushortT*)((char*)ws + WF_B);
  if (gt < 64)  ws[OFF_BN1+64+gt]  += ws[OFF_BN1+gt]     * p.c1b1[gt];
  if (gt < 128){
    ws[OFF_BN1+256+gt] += ws[OFF_BN1+128+gt] * p.c2b1[gt];
    ws[OFF_BN1+512+gt] += ws[OFF_BN1+384+gt] * p.c3b1[gt];
    ws[OFF_BNL1+128+gt] += ws[OFF_BNL1+gt] * p.lb1[gt];
  }
  if (gt < 256) ws[OFF_BNL2+256+gt] += ws[OFF_BNL2+gt] * p.lb2[gt];

  wb_fill(p.c1w,  wf + WF_W1,  64, 64, gt, NT);
  wb_fill(p.c1w1, wf + WF_W1B, 64, 64, gt, NT);
  wb_fill(p.c2w,  wf + WF_W2, 128, 64, gt, NT);
  wb_fill(p.c2w1, wf + WF_W2B,128, 64, gt, NT);
  wb_fill(p.c3w,  wf + WF_W3, 128,128, gt, NT);
  wb_fill(p.c3w1, wf + WF_W3B,128,128, gt, NT);
  wb_fill_hl(p.jw2, wf + WF_JW2H, wf + WF_JW2L, 32, 64, gt, NT);
  wb_fill_hl(p.dw2, wf + WF_DW2H, wf + WF_DW2L, 32, 64, gt, NT);
  wb_fill_hl(ws + OFF_A, wf + WF_AH, wf + WF_AL, 64, 64, gt, NT);
  for (int d_ = gt; d_ < 49152; d_ += NT){
    int j = d_ & 7, l = (d_>>3) & 63, rest = d_ >> 9;
    int ct = rest & 7, kk = (rest>>3) & 3, d = rest>>5;
    int co = ct*16 + (l & 15);
    int ci = kk*32 + (l>>4)*8 + j;
    wf[WF_LW1 + d_] = f2b(p.lw1[(size_t)co*384 + ci*3 + d]);
  }
  for (int d_ = gt; d_ < 32768; d_ += NT){
    int j = d_ & 7, l = (d_>>3) & 63, rest = d_ >> 9;
    int ct = rest & 15, kk = rest >> 4;
    int co = ct*16 + (l & 15);
    int ci = kk*32 + (l>>4)*8 + j;
    wf[WF_LW2 + d_] = f2b(p.lw2[(size_t)co*128 + ci]);
  }
  for (int idx = gt; idx < 8192; idx += NT){
    int t = idx >> 7, co = idx & 127;
    ws[OFF_TMT + idx] = ws[OFF_T1 + co*64 + t];
  }
  for (int i = gt; i < 800; i += NT){
    float v = ws[OFF_S1+i];
    ushortT h = f2b(v);
    wf[WF_SPAH+i] = h; wf[WF_SPAL+i] = f2b(v - b2f(h));
  }
  // transposed final-FC weights (source-linear reads, scattered writes)
  for (int s = gt; s < 2620*256; s += NT){
    int o = s >> 8, c = s & 255;
    float w;
    if (o < 60)        w = p.fcw[s];
    else if (o < 572)  w = p.hww[(size_t)(o-60)*256 + c];
    else if (o < 1084) w = p.pw[(size_t)(o-572)*256 + c];
    else if (o < 1596) w = p.pw[(size_t)(512+(o-1084))*256 + c];
    else if (o < 2108) w = p.pw[(size_t)(1536+(o-1596))*256 + c];
    else               w = p.pw[(size_t)(1024+(o-2108))*256 + c];
    ws[OFF_WT + (size_t)c*2624 + o] = w;
  }
  for (int o = gt; o < 2620; o += NT){
    float bsc;
    if (o < 60)        bsc = p.fcb[o];
    else if (o < 572)  bsc = p.hwb[o-60];
    else if (o < 1084) bsc = p.pb[o-572];
    else if (o < 1596) bsc = p.pb[512+(o-1084)];
    else if (o < 2108) bsc = p.pb[1536+(o-1596)];
    else               bsc = p.pb[1024+(o-2108)];
    ws[OFF_FB + o] = bsc;
  }
}

// ---------------- gcn layer: HILO=1 -> 3-term hi/lo Y; HILO=0 -> hi-only Y ---
template<int KS, int SECS, int L3, int HILO>
__device__ inline void gcn_layer(const s16x8 hf[2][4], const ushortT* WB, const ushortT* W1B,
    const float* bnS, const float* bnO, const s16x8* gfh, const s16x8* gfl,
    ushortT* sYT, ushortT* sHB, const float* tmtt, int lane){
  int l15 = lane & 15, l4 = lane >> 4;
  for (int sec = 0; sec < SECS; sec++){
    f32x4 accY[2][4];
    #pragma unroll
    for (int ut = 0; ut < 2; ut++)
      #pragma unroll
      for (int mt = 0; mt < 4; mt++) accY[ut][mt] = (f32x4){0.f,0.f,0.f,0.f};
    #pragma unroll
    for (int kk = 0; kk < KS; kk++){
      #pragma unroll
      for (int mt = 0; mt < 4; mt++){
        s16x8 bw = *(const s16x8*)(WB + ((size_t)((sec*4+mt)*KS + kk)*64 + lane)*8);
        accY[0][mt] = mfma16(hf[0][kk], bw, accY[0][mt]);
        accY[1][mt] = mfma16(hf[1][kk], bw, accY[1][mt]);
      }
    }
    lfence();  // previous sec's ah/al reads complete before overwrite (WAR)
    #pragma unroll
    for (int ut = 0; ut < 2; ut++){
      #pragma unroll
      for (int mt = 0; mt < 4; mt++){
        unsigned h0 = bbits(accY[ut][mt][0]), h1 = bbits(accY[ut][mt][1]);
        unsigned h2 = bbits(accY[ut][mt][2]), h3 = bbits(accY[ut][mt][3]);
        int base = (mt*16 + l15)*40 + ut*16 + l4*4;
        uint2 hi;
        hi.x = h0 | (h1<<16);  hi.y = h2 | (h3<<16);
        *(uint2*)&sYT[base] = hi;
        if (HILO){
          float l0 = accY[ut][mt][0] - b2f((ushortT)h0);
          float l1 = accY[ut][mt][1] - b2f((ushortT)h1);
          float l2 = accY[ut][mt][2] - b2f((ushortT)h2);
          float l3 = accY[ut][mt][3] - b2f((ushortT)h3);
          uint2 lo;
          lo.x = bbits(l0) | (bbits(l1)<<16);  lo.y = bbits(l2) | (bbits(l3)<<16);
          *(uint2*)&sYT[2560 + base] = lo;
        }
      }
    }
    f32x4 accZ[4][2];
    #pragma unroll
    for (int mt = 0; mt < 4; mt++)
      #pragma unroll
      for (int nt = 0; nt < 2; nt++) accZ[mt][nt] = (f32x4){0.f,0.f,0.f,0.f};
    #pragma unroll
    for (int kk = 0; kk < KS; kk++){
      #pragma unroll
      for (int mt = 0; mt < 4; mt++){
        s16x8 aw = *(const s16x8*)(W1B + ((size_t)((sec*4+mt)*KS + kk)*64 + lane)*8);
        accZ[mt][0] = mfma16(aw, hf[0][kk], accZ[mt][0]);
        accZ[mt][1] = mfma16(aw, hf[1][kk], accZ[mt][1]);
      }
    }
    lfence();  // YT writes visible before ah/al reads (RAW)
    #pragma unroll
    for (int mt = 0; mt < 4; mt++){
      s16x8 ah = *(const s16x8*)&sYT[(mt*16 + l15)*40 + l4*8];
      #pragma unroll
      for (int nt = 0; nt < 2; nt++){
        accZ[mt][nt] = mfma16(ah, gfh[nt], accZ[mt][nt]);
        accZ[mt][nt] = mfma16(ah, gfl[nt], accZ[mt][nt]);
      }
      if (HILO){
        s16x8 al = *(const s16x8*)&sYT[2560 + (mt*16 + l15)*40 + l4*8];
        #pragma unroll
        for (int nt = 0; nt < 2; nt++)
          accZ[mt][nt] = mfma16(al, gfh[nt], accZ[mt][nt]);
      }
    }
    #pragma unroll
    for (int mt = 0; mt < 4; mt++){
      #pragma unroll
      for (int nt = 0; nt < 2; nt++){
        int co0 = sec*64 + mt*16 + l4*4;
        int v = nt*16 + l15;
        float z[4];
        #pragma unroll
        for (int r = 0; r < 4; r++)
          z[r] = fmaxf(bnS[co0+r]*accZ[mt][nt][r] + bnO[co0+r], 0.f);
        if (L3){
          float4 tv = *(const float4*)&tmtt[co0];
          z[0] += tv.x; z[1] += tv.y; z[2] += tv.z; z[3] += tv.w;
        }
        if (v < 25){
          uint2 pk;
          pk.x = bbits(z[0]) | (bbits(z[1])<<16);
          pk.y = bbits(z[2]) | (bbits(z[3])<<16);
          *(uint2*)&sHB[v*HBS + co0] = pk;
        }
      }
    }
  }
}

// ---------------- k_fwd: wave = (b,t) instance -------------------------------
__global__ __launch_bounds__(256, 2) void k_fwd(P p){
  __shared__ __attribute__((aligned(16))) ushortT W1[4][5120];
  __shared__ __attribute__((aligned(16))) ushortT W2[4][4352];
  __shared__ float sBN[640], sBnJ[152], sBnD[152];
  int tid = threadIdx.x, wave = tid >> 6, lane = tid & 63;
  int l15 = lane & 15, l4 = lane >> 4;
  float* ws = p.ws;
  const ushortT* wf = p.wf;
  for (int i = tid; i < 640; i += 256) sBN[i] = ws[OFF_BN1+i];
  for (int i = tid; i < 150; i += 256){ sBnJ[i] = ws[OFF_BNJ+i]; sBnD[i] = ws[OFF_BND+i]; }
  __syncthreads();

  int ic0 = blockIdx.x*4;
  int ic = ic0 + wave;
  int b = ic >> 6, t = ic & 63;
  int n = b >> 1, m = b & 1;
  ushortT* w1 = W1[wave];
  ushortT* w2 = W2[wave];
  float* fw1 = (float*)w1;
  float* fw2 = (float*)w2;

  for (int i = lane; i < 640; i += 64) ((uint4*)w1)[i] = (uint4){0u,0u,0u,0u};
  for (int i = lane; i < 150; i += 64){
    int which = (i < 75) ? 0 : 1;
    int j = i - which*75;
    int c = j/25, vj = j%25;
    int ts = t - which;
    fw2[i] = (ts >= 0) ? p.x[(((n*3+c)*64+ts)*25+vj)*2+m] : 0.f;
  }
  lfence();
  // e1 (lane = o)
  {
    float jwv[3], dwv[3];
    #pragma unroll
    for (int c = 0; c < 3; c++){ jwv[c] = p.jw1[lane*3+c]; dwv[c] = p.dw1[lane*3+c]; }
    float jb = p.jb1[lane], db = p.db1[lane];
    for (int v = 0; v < 25; v++){
      float pa = jb, da = db;
      #pragma unroll
      for (int c = 0; c < 3; c++){
        int ch = c*25+v;
        float xc = fw2[ch];
        float y  = sBnJ[ch]*xc + sBnJ[75+ch];
        float d  = (t > 0) ? (xc - fw2[75+ch]) : 0.f;
        float yd = sBnD[ch]*d + sBnD[75+ch];
        pa += jwv[c]*y;  da += dwv[c]*yd;
      }
      w1[v*72+lane]      = f2b(fmaxf(pa, 0.f));
      w1[2304+v*72+lane] = f2b(fmaxf(da, 0.f));
    }
  }
  lfence();
  s16x8 ep[2][2], ed[2][2];
  #pragma unroll
  for (int mt = 0; mt < 2; mt++)
    #pragma unroll
    for (int kk = 0; kk < 2; kk++){
      ep[mt][kk] = *(const s16x8*)&w1[(mt*16+l15)*72 + kk*32 + l4*8];
      ed[mt][kk] = *(const s16x8*)&w1[2304 + (mt*16+l15)*72 + kk*32 + l4*8];
    }
  f32x4 aP[2][2], aD[2][2];
  #pragma unroll
  for (int mt = 0; mt < 2; mt++)
    #pragma unroll
    for (int nt = 0; nt < 2; nt++){ aP[mt][nt] = (f32x4){0.f,0.f,0.f,0.f}; aD[mt][nt] = (f32x4){0.f,0.f,0.f,0.f}; }
  #pragma unroll
  for (int kk = 0; kk < 2; kk++){
    #pragma unroll
    for (int nt = 0; nt < 2; nt++){
      size_t fo = ((size_t)(nt*2+kk)*64 + lane)*8;
      s16x8 bjh = *(const s16x8*)(wf + WF_JW2H + fo);
      s16x8 bjl = *(const s16x8*)(wf + WF_JW2L + fo);
      s16x8 bdh = *(const s16x8*)(wf + WF_DW2H + fo);
      s16x8 bdl = *(const s16x8*)(wf + WF_DW2L + fo);
      #pragma unroll
      for (int mt = 0; mt < 2; mt++){
        aP[mt][nt] = mfma16(ep[mt][kk], bjh, aP[mt][nt]);
        aP[mt][nt] = mfma16(ep[mt][kk], bjl, aP[mt][nt]);
        aD[mt][nt] = mfma16(ed[mt][kk], bdh, aD[mt][nt]);
        aD[mt][nt] = mfma16(ed[mt][kk], bdl, aD[mt][nt]);
      }
    }
  }
  lfence();
  #pragma unroll
  for (int nt = 0; nt < 2; nt++){
    int c2 = nt*16 + l15;
    float jb2v = p.jb2[c2], db2v = p.db2[c2];
    #pragma unroll
    for (int mt = 0; mt < 2; mt++){
      #pragma unroll
      for (int r = 0; r < 4; r++){
        int v = mt*16 + l4*4 + r;
        if (v < 25){
          float h0 = fmaxf(aP[mt][nt][r]+jb2v, 0.f) + fmaxf(aD[mt][nt][r]+db2v, 0.f);
          ushortT hh = f2b(h0);
          w1[v*72+c2] = hh;
          w1[2304+v*72+c2] = f2b(h0 - b2f(hh));
        }
      }
    }
  }
  for (int i = lane; i < 100; i += 64){
    int v = i >> 2, ch = i & 3;
    *(uint4*)&w1[v*72+32+ch*8]      = *(const uint4*)(wf + WF_SPAH + i*8);
    *(uint4*)&w1[2304+v*72+32+ch*8] = *(const uint4*)(wf + WF_SPAL + i*8);
  }
  lfence();
  s16x8 hfh[2][4], hfl[2][2];
  #pragma unroll
  for (int nt = 0; nt < 2; nt++)
    #pragma unroll
    for (int kk = 0; kk < 2; kk++){
      hfh[nt][kk] = *(const s16x8*)&w1[(nt*16+l15)*72 + kk*32 + l4*8];
      hfl[nt][kk] = *(const s16x8*)&w1[2304 + (nt*16+l15)*72 + kk*32 + l4*8];
    }
  // Cu/Cv
  {
    int up = lane >> 5, r = lane & 31;
    float acc = 0.f;
    if (r < 25){
      const float* cv = ws + OFF_C1 + up*64;
      for (int j8 = 0; j8 < 8; j8++){
        s16x8 hh = *(const s16x8*)&w1[r*72 + j8*8];
        s16x8 ll = *(const s16x8*)&w1[2304 + r*72 + j8*8];
        #pragma unroll
        for (int e = 0; e < 8; e++)
          acc += cv[j8*8+e] * (b2f((ushortT)hh[e]) + b2f((ushortT)ll[e]));
      }
    }
    fw1[2304 + up*32 + r] = acc;
  }
  // Y-GEMM (attention): 3-term
  f32x4 aY[2][4];
  #pragma unroll
  for (int mt = 0; mt < 2; mt++)
    #pragma unroll
    for (int nt = 0; nt < 4; nt++) aY[mt][nt] = (f32x4){0.f,0.f,0.f,0.f};
  #pragma unroll
  for (int kk = 0; kk < 2; kk++){
    #pragma unroll
    for (int nt = 0; nt < 4; nt++){
      size_t fo = ((size_t)(nt*2+kk)*64 + lane)*8;
      s16x8 bah = *(const s16x8*)(wf + WF_AH + fo);
      s16x8 bal = *(const s16x8*)(wf + WF_AL + fo);
      #pragma unroll
      for (int mt = 0; mt < 2; mt++){
        aY[mt][nt] = mfma16(hfh[mt][kk], bah, aY[mt][nt]);
        aY[mt][nt] = mfma16(hfl[mt][kk], bah, aY[mt][nt]);
        aY[mt][nt] = mfma16(hfh[mt][kk], bal, aY[mt][nt]);
      }
    }
  }
  lfence();
  #pragma unroll
  for (int mt = 0; mt < 2; mt++){
    #pragma unroll
    for (int nt = 0; nt < 4; nt++){
      int i_ = nt*16 + l15;
      #pragma unroll
      for (int r = 0; r < 4; r++){
        int u = mt*16 + l4*4 + r;
        float y = aY[mt][nt][r];
        ushortT hh = f2b(y);
        w2[u*72 + i_] = hh;
        w2[2304 + u*64 + (((i_>>3) ^ (u&7))<<3) + (i_&7)] = f2b(y - b2f(hh));
      }
    }
  }
  lfence();
  // S-GEMM: 3-term
  f32x4 aS[2][2];
  #pragma unroll
  for (int mt = 0; mt < 2; mt++)
    #pragma unroll
    for (int nt = 0; nt < 2; nt++) aS[mt][nt] = (f32x4){0.f,0.f,0.f,0.f};
  #pragma unroll
  for (int kk = 0; kk < 2; kk++){
    #pragma unroll
    for (int nt = 0; nt < 2; nt++){
      int ur = nt*16 + l15;
      s16x8 byh = *(const s16x8*)&w2[ur*72 + kk*32 + l4*8];
      s16x8 byl = *(const s16x8*)&w2[2304 + ur*64 + ((((kk*4+l4)) ^ (ur&7))<<3)];
      #pragma unroll
      for (int mt = 0; mt < 2; mt++){
        aS[mt][nt] = mfma16(hfh[mt][kk], byh, aS[mt][nt]);
        aS[mt][nt] = mfma16(hfl[mt][kk], byh, aS[mt][nt]);
        aS[mt][nt] = mfma16(hfh[mt][kk], byl, aS[mt][nt]);
      }
    }
  }
  lfence();
  // softmax + g write (hi @w2[0] stride 40, lo @w2[1280])
  {
    float d0 = ws[OFF_C1+128];
    float cu0 = fw1[2304 + l15];
    float cu1 = fw1[2304 + 16 + l15];
    bool m1 = (16 + l15) < 25;
    #pragma unroll
    for (int mt = 0; mt < 2; mt++){
      #pragma unroll
      for (int r = 0; r < 4; r++){
        int v = mt*16 + l4*4 + r;
        float cvv = (v < 25) ? fw1[2336+v] : 0.f;
        float s0 = aS[mt][0][r] + cu0 + cvv + d0;
        float s1 = m1 ? (aS[mt][1][r] + cu1 + cvv + d0) : -1e30f;
        float mx = fmaxf(s0, s1);
        mx = fmaxf(mx, __shfl_xor(mx, 1));
        mx = fmaxf(mx, __shfl_xor(mx, 2));
        mx = fmaxf(mx, __shfl_xor(mx, 4));
        mx = fmaxf(mx, __shfl_xor(mx, 8));
        float e0 = __expf(s0 - mx);
        float e1v = m1 ? __expf(s1 - mx) : 0.f;
        float sm = e0 + e1v;
        sm += __shfl_xor(sm, 1);
        sm += __shfl_xor(sm, 2);
        sm += __shfl_xor(sm, 4);
        sm += __shfl_xor(sm, 8);
        float inv = 1.f/sm;
        float g0 = e0*inv, g1 = e1v*inv;
        ushortT g0h = f2b(g0), g1h = f2b(g1);
        w2[v*40+l15]         = g0h;
        w2[1280+v*40+l15]    = f2b(g0 - b2f(g0h));
        w2[v*40+16+l15]      = g1h;
        w2[1280+v*40+16+l15] = f2b(g1 - b2f(g1h));
      }
    }
  }
  lfence();
  s16x8 gfh[2], gfl[2];
  #pragma unroll
  for (int nt = 0; nt < 2; nt++){
    gfh[nt] = *(const s16x8*)&w2[(nt*16+l15)*40 + l4*8];
    gfl[nt] = *(const s16x8*)&w2[1280 + (nt*16+l15)*40 + l4*8];
  }
  lfence();   // gf reads done before sHB overwrites w2 (WAR)

  // gcn chain (w1 = YT scratch, w2 = sHB stride HBS, 25 rows, masked reloads)
  const float* tmtt = ws + OFF_TMT + t*128;
  gcn_layer<2,1,0,0>(hfh, wf+WF_W1, wf+WF_W1B, sBN, sBN+64, gfh, gfl, w1, w2, tmtt, lane);
  lfence();
  #pragma unroll
  for (int nt = 0; nt < 2; nt++){
    int v = nt*16 + l15;
    int vr = (v < 25) ? v : 0;
    #pragma unroll
    for (int kk = 0; kk < 2; kk++){
      s16x8 tv = *(const s16x8*)&w2[vr*HBS + kk*32 + l4*8];
      s16x8 z = {0,0,0,0,0,0,0,0};
      hfh[nt][kk] = (v < 25) ? tv : z;
    }
  }
  lfence();
  gcn_layer<2,2,0,0>(hfh, wf+WF_W2, wf+WF_W2B, sBN+128, sBN+256, gfh, gfl, w1, w2, tmtt, lane);
  lfence();
  #pragma unroll
  for (int nt = 0; nt < 2; nt++){
    int v = nt*16 + l15;
    int vr = (v < 25) ? v : 0;
    #pragma unroll
    for (int kk = 0; kk < 4; kk++){
      s16x8 tv = *(const s16x8*)&w2[vr*HBS + kk*32 + l4*8];
      s16x8 z = {0,0,0,0,0,0,0,0};
      hfh[nt][kk] = (v < 25) ? tv : z;
    }
  }
  lfence();
  gcn_layer<4,2,1,1>(hfh, wf+WF_W3, wf+WF_W3B, sBN+384, sBN+512, gfh, gfl, w1, w2, tmtt, lane);

  __syncthreads();
  int bb = ic0 >> 6, sg = (ic0 & 63) >> 2;
  for (int i = tid; i < 3200; i += 256){
    int v = i >> 7, co = i & 127;
    float mx =     b2f(W2[0][v*HBS+co]);
    mx = fmaxf(mx, b2f(W2[1][v*HBS+co]));
    mx = fmaxf(mx, b2f(W2[2][v*HBS+co]));
    mx = fmaxf(mx, b2f(W2[3][v*HBS+co]));
    p.poolb[(((size_t)bb*16+sg)*25+v)*128 + co] = f2b(mx);
  }
}

// ---------------- k_lc: fused loc (conv3 + 1x1 + sum_s), wave = (b,v) --------
__global__ __launch_bounds__(256) void k_lc(P p){
  __shared__ ushortT sA[4][2448];
  __shared__ ushortT sO[4][2176];
  __shared__ float sB1[256], sB2[512];
  int tid = threadIdx.x, wave = tid >> 6, lane = tid & 63;
  int l15 = lane & 15, l4 = lane >> 4;
  int tk = blockIdx.x*4 + wave;
  int b = tk / 25, v = tk % 25;
  float* ws = p.ws;
  if (tid < 256) sB1[tid] = ws[OFF_BNL1 + tid];
  for (int i = tid; i < 512; i += 256) sB2[i] = ws[OFF_BNL2 + i];
  __syncthreads();

  ushortT* A = sA[wave];
  ushortT* O = sO[wave];
  for (int i = lane; i < 68; i += 64){
    *(unsigned*)&A[i*2] = 0u;
    *(unsigned*)&A[2312 + i*2] = 0u;
  }
  for (int i = lane; i < 256; i += 64){
    int r = i >> 4, c8 = i & 15;
    *(uint4*)&A[(r+1)*136 + c8*8] =
      *(const uint4*)&p.poolb[((size_t)(b*16+r)*25 + v)*128 + c8*8];
  }
  lfence();
  const ushortT* lw1f = p.wf + WF_LW1;
  const ushortT* lw2f = p.wf + WF_LW2;

  f32x4 a1[8];
  #pragma unroll
  for (int ct = 0; ct < 8; ct++) a1[ct] = (f32x4){0.f,0.f,0.f,0.f};
  #pragma unroll
  for (int d = 0; d < 3; d++){
    #pragma unroll
    for (int kk = 0; kk < 4; kk++){
      s16x8 af = *(const s16x8*)&A[(l15+d)*136 + kk*32 + l4*8];
      #pragma unroll
      for (int ct = 0; ct < 8; ct++){
        s16x8 bf = *(const s16x8*)(lw1f + (size_t)(((d*4+kk)*8+ct)*512 + lane*8));
        a1[ct] = mfma16(af, bf, a1[ct]);
      }
    }
  }
  #pragma unroll
  for (int ct = 0; ct < 8; ct++){
    int co = ct*16 + l15;
    float s1 = sB1[co], o1 = sB1[128+co];
    #pragma unroll
    for (int r = 0; r < 4; r++)
      O[(l4*4+r)*136 + co] = f2b(fmaxf(s1*a1[ct][r] + o1, 0.f));
  }
  lfence();
  s16x8 af2[4];
  #pragma unroll
  for (int kk = 0; kk < 4; kk++)
    af2[kk] = *(const s16x8*)&O[l15*136 + kk*32 + l4*8];
  f32x4 a2[16];
  #pragma unroll
  for (int ct = 0; ct < 16; ct++) a2[ct] = (f32x4){0.f,0.f,0.f,0.f};
  #pragma unroll
  for (int kk = 0; kk < 4; kk++){
    #pragma unroll
    for (int ct = 0; ct < 16; ct++){
      s16x8 bf = *(const s16x8*)(lw2f + (size_t)((kk*16+ct)*512 + lane*8));
      a2[ct] = mfma16(af2[kk], bf, a2[ct]);
    }
  }
  #pragma unroll
  for (int ct = 0; ct < 16; ct++){
    int co = ct*16 + l15;
    float s2 = sB2[co], o2 = sB2[256+co];
    float sum = 0.f;
    #pragma unroll
    for (int r = 0; r < 4; r++) sum += fmaxf(s2*a2[ct][r] + o2, 0.f);
    sum += __shfl_xor(sum, 16);
    sum += __shfl_xor(sum, 32);
    if (lane < 16) ws[OFF_PART2 + (size_t)(b*25+v)*256 + co] = sum;
  }
}

// ---------------- k_fc: pool (inline) + FC heads, 1408 blocks ----------------
__global__ __launch_bounds__(256) void k_fc(P p){
  __shared__ float sp[5*257];
  int tid = threadIdx.x;
  int n = blockIdx.x & 127, ch = blockIdx.x >> 7;
  const float* part = p.ws + OFF_PART2;
  float tot = 0.f, hd = 0.f, hn = 0.f, ft = 0.f, hq = 0.f;
  for (int m2 = 0; m2 < 2; m2++){
    for (int v = 0; v < 25; v++){
      float pv = part[(size_t)((n*2+m2)*25+v)*256 + tid];
      tot += pv;
      unsigned bit = 1u << v;
      if (bit & 0x10000Cu)  hd += pv;
      if (bit & 0x1E00FF0u) hn += pv;
      if (bit & 0xFF000u)   ft += pv;
      if (bit & 0x11007u)   hq += pv;
    }
  }
  sp[tid]         = tot * (1.f/800.f);
  sp[257+tid]     = hd  * (1.f/96.f);
  sp[2*257+tid]   = hn  * (1.f/384.f);
  sp[3*257+tid]   = ft  * (1.f/256.f);
  sp[4*257+tid]   = hq  * (1.f/160.f);
  __syncthreads();
  int o = ch*256 + tid;
  if (o < 2620){
    int sel, off;
    if (o < 60)        { sel = 0; off = n*60+o; }
    else if (o < 572)  { sel = 0; off = 7680   + n*512+(o-60); }
    else if (o < 1084) { sel = 1; off = 73221  + n*512+(o-572); }
    else if (o < 1596) { sel = 2; off = 138757 + n*512+(o-1084); }
    else if (o < 2108) { sel = 4; off = 204293 + n*512+(o-1596); }
    else               { sel = 3; off = 269829 + n*512+(o-2108); }
    const float* pl = sp + sel*257;
    const float* wo = p.ws + OFF_WT + o;
    float acc = p.ws[OFF_FB + o];
    #pragma unroll 8
    for (int c = 0; c < 256; c++) acc += wo[(size_t)c*2624] * pl[c];
    p.out[off] = acc;
  }
  if (blockIdx.x == 0 && tid < 5) p.out[73216+tid] = p.ls[tid];
}

extern "C" void kernel_launch(void* const* d_in, const int* in_sizes, int n_in,
                              void* d_out, int out_size, void* d_ws, size_t ws_size,
                              hipStream_t stream){
  P p;
  p.x        = (const float*)d_in[0];
  p.bn_joint = (const float*)d_in[1];
  p.jw1      = (const float*)d_in[2];
  p.jb1      = (const float*)d_in[3];
  p.jw2      = (const float*)d_in[4];
  p.jb2      = (const float*)d_in[5];
  p.bn_dif   = (const float*)d_in[6];
  p.dw1      = (const float*)d_in[7];
  p.db1      = (const float*)d_in[8];
  p.dw2      = (const float*)d_in[9];
  p.db2      = (const float*)d_in[10];
  p.tw1      = (const float*)d_in[11];
  p.tb1      = (const float*)d_in[12];
  p.tw2      = (const float*)d_in[13];
  p.tb2      = (const float*)d_in[14];
  p.sw1      = (const float*)d_in[15];
  p.sb1      = (const float*)d_in[16];
  p.sw2      = (const float*)d_in[17];
  p.sb2      = (const float*)d_in[18];
  p.g1w      = (const float*)d_in[19];
  p.g1b      = (const float*)d_in[20];
  p.g2w      = (const float*)d_in[21];
  p.g2b      = (const float*)d_in[22];
  p.c1w      = (const float*)d_in[23];
  p.c1w1     = (const float*)d_in[24];
  p.c1b1     = (const float*)d_in[25];
  p.bnc1     = (const float*)d_in[26];
  p.c2w      = (const float*)d_in[27];
  p.c2w1     = (const float*)d_in[28];
  p.c2b1     = (const float*)d_in[29];
  p.bnc2     = (const float*)d_in[30];
  p.c3w      = (const float*)d_in[31];
  p.c3w1     = (const float*)d_in[32];
  p.c3b1     = (const float*)d_in[33];
  p.bnc3     = (const float*)d_in[34];
  p.lw1      = (const float*)d_in[35];
  p.lb1      = (const float*)d_in[36];
  p.bnl1     = (const float*)d_in[37];
  p.lw2      = (const float*)d_in[38];
  p.lb2      = (const float*)d_in[39];
  p.bnl2     = (const float*)d_in[40];
  p.fcw      = (const float*)d_in[41];
  p.fcb      = (const float*)d_in[42];
  p.hww      = (const float*)d_in[43];
  p.hwb      = (const float*)d_in[44];
  p.pw       = (const float*)d_in[45];
  p.pb       = (const float*)d_in[46];
  p.ls       = (const float*)d_in[47];
  p.ws  = (float*)d_ws;
  p.out = (float*)d_out;

  char* wsb = (char*)d_ws;
  p.wf    = (const ushortT*)(wsb + WF_B);
  p.poolb = (ushortT*)(wsb + POOL_B);

  k_pre1 <<<dim3(32),   dim3(256), 0, stream>>>(p);
  k_pre2 <<<dim3(32),   dim3(256), 0, stream>>>(p);
  k_fwd  <<<dim3(4096), dim3(256), 0, stream>>>(p);
  k_lc   <<<dim3(1600), dim3(256), 0, stream>>>(p);
  k_fc   <<<dim3(1408), dim3(256), 0, stream>>>(p);
}

// Round 18
// 403.427 us; speedup vs baseline: 1.0160x; 1.0160x over previous
//
#include <hip/hip_runtime.h>

#define EPS 1e-5f

// table float offsets
#define OFF_S1   0
#define OFF_T1   800
#define OFF_A    8992
#define OFF_C1   13088
#define OFF_BNJ  13217
#define OFF_BND  13367
#define OFF_BN1  13517
#define OFF_BNL1 14157
#define OFF_BNL2 14413
#define OFF_CUS  14928
#define OFF_TMT  16384      // [64t][128co] f32

// byte layout
#define WF_B     98304
#define POOL_B   458752
#define PART_B   (POOL_B + 26214400)
#define OFF_PART2 (PART_B/4)
#define WT_B     (PART_B + 6553600)
#define OFF_WT   (WT_B/4)
#define OFF_FB   (OFF_WT + 256*2624)

// WF ush offsets
#define WF_W1    0
#define WF_W1B   4096
#define WF_W2    8192
#define WF_W2B   16384
#define WF_W3    24576
#define WF_W3B   40960
#define WF_LW1   57344
#define WF_LW2   106496
#define WF_JW2H  139264
#define WF_JW2L  141312
#define WF_DW2H  143360
#define WF_DW2L  145408
#define WF_AH    147456
#define WF_AL    151552
#define WF_SPAH  155648
#define WF_SPAL  156448

#define HBS 152   // sHB row stride (ush): 76 dw -> 2-way bank aliasing (free)

typedef unsigned short ushortT;
typedef float  f32x4 __attribute__((ext_vector_type(4)));
typedef short  s16x8 __attribute__((ext_vector_type(8)));

struct P {
  const float *x,*bn_joint,*jw1,*jb1,*jw2,*jb2,*bn_dif,*dw1,*db1,*dw2,*db2,
    *tw1,*tb1,*tw2,*tb2,*sw1,*sb1,*sw2,*sb2,*g1w,*g1b,*g2w,*g2b,
    *c1w,*c1w1,*c1b1,*bnc1,*c2w,*c2w1,*c2b1,*bnc2,*c3w,*c3w1,*c3b1,*bnc3,
    *lw1,*lb1,*bnl1,*lw2,*lb2,*bnl2,*fcw,*fcb,*hww,*hwb,*pw,*pb,*ls;
  float *ws, *out;
  const ushortT* wf;
  ushortT *poolb;
};

// LDS-only ordering fence: waits LDS ops (lgkmcnt) without draining the
// global-load queue (vmcnt), unlike __threadfence_block. sched_barrier(0)
// pins compiler scheduling across the asm (guide rule #18).
__device__ inline void lfence(){
  asm volatile("s_waitcnt lgkmcnt(0)" ::: "memory");
  __builtin_amdgcn_sched_barrier(0);
}

__device__ inline unsigned bbits(float x){
  union{float f;unsigned u;} a; a.f = x;
  return ((a.u + 0x7fffu + ((a.u>>16)&1u))>>16) & 0xffffu;
}
__device__ inline ushortT f2b(float x){ return (ushortT)bbits(x); }
__device__ inline float b2f(ushortT b){
  union{unsigned u;float f;} a; a.u = ((unsigned)b)<<16; return a.f;
}
__device__ inline f32x4 mfma16(s16x8 a, s16x8 b, f32x4 c){
  return __builtin_amdgcn_mfma_f32_16x16x32_bf16(a, b, c, 0, 0, 0);
}

__device__ inline void bn_pre(const float* bn, int C, float* dst, int gt, int NT){
  for (int c = gt; c < C; c += NT){
    float g = bn[c], b = bn[C+c], m = bn[2*C+c], v = bn[3*C+c];
    float s = g * rsqrtf(v + EPS);
    dst[c] = s; dst[C+c] = b - m*s;
  }
}

__device__ inline void wb_fill(const float* src, ushortT* dst, int COUT, int CIN, int gt, int NT){
  int KS = CIN/32;
  int total = COUT*CIN;
  for (int d = gt; d < total; d += NT){
    int j = d & 7, l = (d>>3) & 63, rest = d >> 9;
    int kk = rest % KS, tile = rest / KS;
    int co = tile*16 + (l & 15);
    int k  = kk*32 + (l >> 4)*8 + j;
    dst[d] = f2b(src[(size_t)co*CIN + k]);
  }
}

__device__ inline void wb_fill_hl(const float* src, ushortT* dh, ushortT* dl, int COUT, int CIN, int gt, int NT){
  int KS = CIN/32;
  int total = COUT*CIN;
  for (int d = gt; d < total; d += NT){
    int j = d & 7, l = (d>>3) & 63, rest = d >> 9;
    int kk = rest % KS, tile = rest / KS;
    int co = tile*16 + (l & 15);
    int k  = kk*32 + (l >> 4)*8 + j;
    float v = src[(size_t)co*CIN + k];
    ushortT h = f2b(v);
    dh[d] = h; dl[d] = f2b(v - b2f(h));
  }
}

__global__ __launch_bounds__(256) void k_pre1(P p){
  int gt = blockIdx.x*256 + threadIdx.x, NT = gridDim.x*256;
  float* ws = p.ws;
  bn_pre(p.bn_joint, 75, ws+OFF_BNJ, gt, NT);
  bn_pre(p.bn_dif,   75, ws+OFF_BND, gt, NT);
  bn_pre(p.bnc1,     64, ws+OFF_BN1, gt, NT);
  bn_pre(p.bnc2,    128, ws+OFF_BN1+128, gt, NT);
  bn_pre(p.bnc3,    128, ws+OFF_BN1+384, gt, NT);
  bn_pre(p.bnl1,    128, ws+OFF_BNL1, gt, NT);
  bn_pre(p.bnl2,    256, ws+OFF_BNL2, gt, NT);
  for (int idx = gt; idx < 800; idx += NT){
    int v = idx >> 5, o2 = idx & 31;
    float acc = p.sb2[o2];
    for (int o = 0; o < 64; o++){
      float e = fmaxf(p.sw1[o*25+v] + p.sb1[o], 0.f);
      acc += p.sw2[o2*64+o] * e;
    }
    ws[OFF_S1+idx] = fmaxf(acc, 0.f);
  }
  for (int idx = gt; idx < 8192; idx += NT){
    int o = idx / 64, t = idx % 64;
    float acc = p.tb2[o];
    for (int o1 = 0; o1 < 64; o1++){
      float e = fmaxf(p.tw1[o1*64+t] + p.tb1[o1], 0.f);
      acc += p.tw2[o*64+o1] * e;
    }
    ws[OFF_T1+idx] = fmaxf(acc, 0.f);
  }
  for (int idx = gt; idx < 4096; idx += NT){
    int i = idx / 64, j = idx % 64;
    float acc = 0.f;
    for (int c = 0; c < 128; c++) acc += p.g1w[c*64+i] * p.g2w[c*64+j];
    ws[OFF_A+idx] = acc;
  }
  if (gt < 64){
    float a = 0.f; for (int c = 0; c < 128; c++) a += p.g1b[c]*p.g2w[c*64+gt];
    ws[OFF_C1+gt] = a;
  } else if (gt < 128){
    int j = gt - 64;
    float a = 0.f; for (int c = 0; c < 128; c++) a += p.g2b[c]*p.g1w[c*64+j];
    ws[OFF_C1+64+j] = a;
  } else if (gt == 128){
    float a = 0.f; for (int c = 0; c < 128; c++) a += p.g1b[c]*p.g2b[c];
    ws[OFF_C1+128] = a;
  }
}

__global__ __launch_bounds__(256) void k_pre2(P p){
  int gt = blockIdx.x*256 + threadIdx.x, NT = gridDim.x*256;
  float* ws = p.ws;
  ushortT* wf = (ushortT*)((char*)ws + WF_B);
  if (gt < 64)  ws[OFF_BN1+64+gt]  += ws[OFF_BN1+gt]     * p.c1b1[gt];
  if (gt < 128){
    ws[OFF_BN1+256+gt] += ws[OFF_BN1+128+gt] * p.c2b1[gt];
    ws[OFF_BN1+512+gt] += ws[OFF_BN1+384+gt] * p.c3b1[gt];
    ws[OFF_BNL1+128+gt] += ws[OFF_BNL1+gt] * p.lb1[gt];
  }
  if (gt < 256) ws[OFF_BNL2+256+gt] += ws[OFF_BNL2+gt] * p.lb2[gt];

  wb_fill(p.c1w,  wf + WF_W1,  64, 64, gt, NT);
  wb_fill(p.c1w1, wf + WF_W1B, 64, 64, gt, NT);
  wb_fill(p.c2w,  wf + WF_W2, 128, 64, gt, NT);
  wb_fill(p.c2w1, wf + WF_W2B,128, 64, gt, NT);
  wb_fill(p.c3w,  wf + WF_W3, 128,128, gt, NT);
  wb_fill(p.c3w1, wf + WF_W3B,128,128, gt, NT);
  wb_fill_hl(p.jw2, wf + WF_JW2H, wf + WF_JW2L, 32, 64, gt, NT);
  wb_fill_hl(p.dw2, wf + WF_DW2H, wf + WF_DW2L, 32, 64, gt, NT);
  wb_fill_hl(ws + OFF_A, wf + WF_AH, wf + WF_AL, 64, 64, gt, NT);
  for (int d_ = gt; d_ < 49152; d_ += NT){
    int j = d_ & 7, l = (d_>>3) & 63, rest = d_ >> 9;
    int ct = rest & 7, kk = (rest>>3) & 3, d = rest>>5;
    int co = ct*16 + (l & 15);
    int ci = kk*32 + (l>>4)*8 + j;
    wf[WF_LW1 + d_] = f2b(p.lw1[(size_t)co*384 + ci*3 + d]);
  }
  for (int d_ = gt; d_ < 32768; d_ += NT){
    int j = d_ & 7, l = (d_>>3) & 63, rest = d_ >> 9;
    int ct = rest & 15, kk = rest >> 4;
    int co = ct*16 + (l & 15);
    int ci = kk*32 + (l>>4)*8 + j;
    wf[WF_LW2 + d_] = f2b(p.lw2[(size_t)co*128 + ci]);
  }
  for (int idx = gt; idx < 8192; idx += NT){
    int t = idx >> 7, co = idx & 127;
    ws[OFF_TMT + idx] = ws[OFF_T1 + co*64 + t];
  }
  for (int i = gt; i < 800; i += NT){
    float v = ws[OFF_S1+i];
    ushortT h = f2b(v);
    wf[WF_SPAH+i] = h; wf[WF_SPAL+i] = f2b(v - b2f(h));
  }
  // transposed final-FC weights (source-linear reads, scattered writes)
  for (int s = gt; s < 2620*256; s += NT){
    int o = s >> 8, c = s & 255;
    float w;
    if (o < 60)        w = p.fcw[s];
    else if (o < 572)  w = p.hww[(size_t)(o-60)*256 + c];
    else if (o < 1084) w = p.pw[(size_t)(o-572)*256 + c];
    else if (o < 1596) w = p.pw[(size_t)(512+(o-1084))*256 + c];
    else if (o < 2108) w = p.pw[(size_t)(1536+(o-1596))*256 + c];
    else               w = p.pw[(size_t)(1024+(o-2108))*256 + c];
    ws[OFF_WT + (size_t)c*2624 + o] = w;
  }
  for (int o = gt; o < 2620; o += NT){
    float bsc;
    if (o < 60)        bsc = p.fcb[o];
    else if (o < 572)  bsc = p.hwb[o-60];
    else if (o < 1084) bsc = p.pb[o-572];
    else if (o < 1596) bsc = p.pb[512+(o-1084)];
    else if (o < 2108) bsc = p.pb[1536+(o-1596)];
    else               bsc = p.pb[1024+(o-2108)];
    ws[OFF_FB + o] = bsc;
  }
}

// ---------------- gcn layer: HILO=1 -> 3-term hi/lo Y; HILO=0 -> hi-only Y ---
template<int KS, int SECS, int L3, int HILO>
__device__ inline void gcn_layer(const s16x8 hf[2][4], const ushortT* WB, const ushortT* W1B,
    const float* bnS, const float* bnO, const s16x8* gfh, const s16x8* gfl,
    ushortT* sYT, ushortT* sHB, const float* tmtt, int lane){
  int l15 = lane & 15, l4 = lane >> 4;
  for (int sec = 0; sec < SECS; sec++){
    f32x4 accY[2][4];
    #pragma unroll
    for (int ut = 0; ut < 2; ut++)
      #pragma unroll
      for (int mt = 0; mt < 4; mt++) accY[ut][mt] = (f32x4){0.f,0.f,0.f,0.f};
    #pragma unroll
    for (int kk = 0; kk < KS; kk++){
      #pragma unroll
      for (int mt = 0; mt < 4; mt++){
        s16x8 bw = *(const s16x8*)(WB + ((size_t)((sec*4+mt)*KS + kk)*64 + lane)*8);
        accY[0][mt] = mfma16(hf[0][kk], bw, accY[0][mt]);
        accY[1][mt] = mfma16(hf[1][kk], bw, accY[1][mt]);
      }
    }
    lfence();  // previous sec's ah/al reads complete before overwrite (WAR)
    #pragma unroll
    for (int ut = 0; ut < 2; ut++){
      #pragma unroll
      for (int mt = 0; mt < 4; mt++){
        unsigned h0 = bbits(accY[ut][mt][0]), h1 = bbits(accY[ut][mt][1]);
        unsigned h2 = bbits(accY[ut][mt][2]), h3 = bbits(accY[ut][mt][3]);
        int base = (mt*16 + l15)*40 + ut*16 + l4*4;
        uint2 hi;
        hi.x = h0 | (h1<<16);  hi.y = h2 | (h3<<16);
        *(uint2*)&sYT[base] = hi;
        if (HILO){
          float l0 = accY[ut][mt][0] - b2f((ushortT)h0);
          float l1 = accY[ut][mt][1] - b2f((ushortT)h1);
          float l2 = accY[ut][mt][2] - b2f((ushortT)h2);
          float l3 = accY[ut][mt][3] - b2f((ushortT)h3);
          uint2 lo;
          lo.x = bbits(l0) | (bbits(l1)<<16);  lo.y = bbits(l2) | (bbits(l3)<<16);
          *(uint2*)&sYT[2560 + base] = lo;
        }
      }
    }
    f32x4 accZ[4][2];
    #pragma unroll
    for (int mt = 0; mt < 4; mt++)
      #pragma unroll
      for (int nt = 0; nt < 2; nt++) accZ[mt][nt] = (f32x4){0.f,0.f,0.f,0.f};
    #pragma unroll
    for (int kk = 0; kk < KS; kk++){
      #pragma unroll
      for (int mt = 0; mt < 4; mt++){
        s16x8 aw = *(const s16x8*)(W1B + ((size_t)((sec*4+mt)*KS + kk)*64 + lane)*8);
        accZ[mt][0] = mfma16(aw, hf[0][kk], accZ[mt][0]);
        accZ[mt][1] = mfma16(aw, hf[1][kk], accZ[mt][1]);
      }
    }
    lfence();  // YT writes visible before ah/al reads (RAW)
    #pragma unroll
    for (int mt = 0; mt < 4; mt++){
      s16x8 ah = *(const s16x8*)&sYT[(mt*16 + l15)*40 + l4*8];
      #pragma unroll
      for (int nt = 0; nt < 2; nt++){
        accZ[mt][nt] = mfma16(ah, gfh[nt], accZ[mt][nt]);
        accZ[mt][nt] = mfma16(ah, gfl[nt], accZ[mt][nt]);
      }
      if (HILO){
        s16x8 al = *(const s16x8*)&sYT[2560 + (mt*16 + l15)*40 + l4*8];
        #pragma unroll
        for (int nt = 0; nt < 2; nt++)
          accZ[mt][nt] = mfma16(al, gfh[nt], accZ[mt][nt]);
      }
    }
    #pragma unroll
    for (int mt = 0; mt < 4; mt++){
      #pragma unroll
      for (int nt = 0; nt < 2; nt++){
        int co0 = sec*64 + mt*16 + l4*4;
        int v = nt*16 + l15;
        float z[4];
        #pragma unroll
        for (int r = 0; r < 4; r++)
          z[r] = fmaxf(bnS[co0+r]*accZ[mt][nt][r] + bnO[co0+r], 0.f);
        if (L3){
          float4 tv = *(const float4*)&tmtt[co0];
          z[0] += tv.x; z[1] += tv.y; z[2] += tv.z; z[3] += tv.w;
        }
        if (v < 25){
          uint2 pk;
          pk.x = bbits(z[0]) | (bbits(z[1])<<16);
          pk.y = bbits(z[2]) | (bbits(z[3])<<16);
          *(uint2*)&sHB[v*HBS + co0] = pk;
        }
      }
    }
  }
}

// ---------------- k_fwd: wave = (b,t) instance -------------------------------
__global__ __launch_bounds__(256, 2) void k_fwd(P p){
  __shared__ __attribute__((aligned(16))) ushortT W1[4][5120];
  __shared__ __attribute__((aligned(16))) ushortT W2[4][4352];
  __shared__ float sBN[640], sBnJ[152], sBnD[152];
  int tid = threadIdx.x, wave = tid >> 6, lane = tid & 63;
  int l15 = lane & 15, l4 = lane >> 4;
  float* ws = p.ws;
  const ushortT* wf = p.wf;
  for (int i = tid; i < 640; i += 256) sBN[i] = ws[OFF_BN1+i];
  for (int i = tid; i < 150; i += 256){ sBnJ[i] = ws[OFF_BNJ+i]; sBnD[i] = ws[OFF_BND+i]; }
  __syncthreads();

  int ic0 = blockIdx.x*4;
  int ic = ic0 + wave;
  int b = ic >> 6, t = ic & 63;
  int n = b >> 1, m = b & 1;
  ushortT* w1 = W1[wave];
  ushortT* w2 = W2[wave];
  float* fw1 = (float*)w1;
  float* fw2 = (float*)w2;

  for (int i = lane; i < 640; i += 64) ((uint4*)w1)[i] = (uint4){0u,0u,0u,0u};
  for (int i = lane; i < 150; i += 64){
    int which = (i < 75) ? 0 : 1;
    int j = i - which*75;
    int c = j/25, vj = j%25;
    int ts = t - which;
    fw2[i] = (ts >= 0) ? p.x[(((n*3+c)*64+ts)*25+vj)*2+m] : 0.f;
  }
  lfence();
  // e1 (lane = o)
  {
    float jwv[3], dwv[3];
    #pragma unroll
    for (int c = 0; c < 3; c++){ jwv[c] = p.jw1[lane*3+c]; dwv[c] = p.dw1[lane*3+c]; }
    float jb = p.jb1[lane], db = p.db1[lane];
    for (int v = 0; v < 25; v++){
      float pa = jb, da = db;
      #pragma unroll
      for (int c = 0; c < 3; c++){
        int ch = c*25+v;
        float xc = fw2[ch];
        float y  = sBnJ[ch]*xc + sBnJ[75+ch];
        float d  = (t > 0) ? (xc - fw2[75+ch]) : 0.f;
        float yd = sBnD[ch]*d + sBnD[75+ch];
        pa += jwv[c]*y;  da += dwv[c]*yd;
      }
      w1[v*72+lane]      = f2b(fmaxf(pa, 0.f));
      w1[2304+v*72+lane] = f2b(fmaxf(da, 0.f));
    }
  }
  lfence();
  s16x8 ep[2][2], ed[2][2];
  #pragma unroll
  for (int mt = 0; mt < 2; mt++)
    #pragma unroll
    for (int kk = 0; kk < 2; kk++){
      ep[mt][kk] = *(const s16x8*)&w1[(mt*16+l15)*72 + kk*32 + l4*8];
      ed[mt][kk] = *(const s16x8*)&w1[2304 + (mt*16+l15)*72 + kk*32 + l4*8];
    }
  f32x4 aP[2][2], aD[2][2];
  #pragma unroll
  for (int mt = 0; mt < 2; mt++)
    #pragma unroll
    for (int nt = 0; nt < 2; nt++){ aP[mt][nt] = (f32x4){0.f,0.f,0.f,0.f}; aD[mt][nt] = (f32x4){0.f,0.f,0.f,0.f}; }
  #pragma unroll
  for (int kk = 0; kk < 2; kk++){
    #pragma unroll
    for (int nt = 0; nt < 2; nt++){
      size_t fo = ((size_t)(nt*2+kk)*64 + lane)*8;
      s16x8 bjh = *(const s16x8*)(wf + WF_JW2H + fo);
      s16x8 bjl = *(const s16x8*)(wf + WF_JW2L + fo);
      s16x8 bdh = *(const s16x8*)(wf + WF_DW2H + fo);
      s16x8 bdl = *(const s16x8*)(wf + WF_DW2L + fo);
      #pragma unroll
      for (int mt = 0; mt < 2; mt++){
        aP[mt][nt] = mfma16(ep[mt][kk], bjh, aP[mt][nt]);
        aP[mt][nt] = mfma16(ep[mt][kk], bjl, aP[mt][nt]);
        aD[mt][nt] = mfma16(ed[mt][kk], bdh, aD[mt][nt]);
        aD[mt][nt] = mfma16(ed[mt][kk], bdl, aD[mt][nt]);
      }
    }
  }
  lfence();
  #pragma unroll
  for (int nt = 0; nt < 2; nt++){
    int c2 = nt*16 + l15;
    float jb2v = p.jb2[c2], db2v = p.db2[c2];
    #pragma unroll
    for (int mt = 0; mt < 2; mt++){
      #pragma unroll
      for (int r = 0; r < 4; r++){
        int v = mt*16 + l4*4 + r;
        if (v < 25){
          float h0 = fmaxf(aP[mt][nt][r]+jb2v, 0.f) + fmaxf(aD[mt][nt][r]+db2v, 0.f);
          ushortT hh = f2b(h0);
          w1[v*72+c2] = hh;
          w1[2304+v*72+c2] = f2b(h0 - b2f(hh));
        }
      }
    }
  }
  for (int i = lane; i < 100; i += 64){
    int v = i >> 2, ch = i & 3;
    *(uint4*)&w1[v*72+32+ch*8]      = *(const uint4*)(wf + WF_SPAH + i*8);
    *(uint4*)&w1[2304+v*72+32+ch*8] = *(const uint4*)(wf + WF_SPAL + i*8);
  }
  lfence();
  s16x8 hfh[2][4], hfl[2][2];
  #pragma unroll
  for (int nt = 0; nt < 2; nt++)
    #pragma unroll
    for (int kk = 0; kk < 2; kk++){
      hfh[nt][kk] = *(const s16x8*)&w1[(nt*16+l15)*72 + kk*32 + l4*8];
      hfl[nt][kk] = *(const s16x8*)&w1[2304 + (nt*16+l15)*72 + kk*32 + l4*8];
    }
  // Cu/Cv
  {
    int up = lane >> 5, r = lane & 31;
    float acc = 0.f;
    if (r < 25){
      const float* cv = ws + OFF_C1 + up*64;
      for (int j8 = 0; j8 < 8; j8++){
        s16x8 hh = *(const s16x8*)&w1[r*72 + j8*8];
        s16x8 ll = *(const s16x8*)&w1[2304 + r*72 + j8*8];
        #pragma unroll
        for (int e = 0; e < 8; e++)
          acc += cv[j8*8+e] * (b2f((ushortT)hh[e]) + b2f((ushortT)ll[e]));
      }
    }
    fw1[2304 + up*32 + r] = acc;
  }
  // Y-GEMM (attention): 3-term
  f32x4 aY[2][4];
  #pragma unroll
  for (int mt = 0; mt < 2; mt++)
    #pragma unroll
    for (int nt = 0; nt < 4; nt++) aY[mt][nt] = (f32x4){0.f,0.f,0.f,0.f};
  #pragma unroll
  for (int kk = 0; kk < 2; kk++){
    #pragma unroll
    for (int nt = 0; nt < 4; nt++){
      size_t fo = ((size_t)(nt*2+kk)*64 + lane)*8;
      s16x8 bah = *(const s16x8*)(wf + WF_AH + fo);
      s16x8 bal = *(const s16x8*)(wf + WF_AL + fo);
      #pragma unroll
      for (int mt = 0; mt < 2; mt++){
        aY[mt][nt] = mfma16(hfh[mt][kk], bah, aY[mt][nt]);
        aY[mt][nt] = mfma16(hfl[mt][kk], bah, aY[mt][nt]);
        aY[mt][nt] = mfma16(hfh[mt][kk], bal, aY[mt][nt]);
      }
    }
  }
  lfence();
  #pragma unroll
  for (int mt = 0; mt < 2; mt++){
    #pragma unroll
    for (int nt = 0; nt < 4; nt++){
      int i_ = nt*16 + l15;
      #pragma unroll
      for (int r = 0; r < 4; r++){
        int u = mt*16 + l4*4 + r;
        float y = aY[mt][nt][r];
        ushortT hh = f2b(y);
        w2[u*72 + i_] = hh;
        w2[2304 + u*64 + (((i_>>3) ^ (u&7))<<3) + (i_&7)] = f2b(y - b2f(hh));
      }
    }
  }
  lfence();
  // S-GEMM: 3-term
  f32x4 aS[2][2];
  #pragma unroll
  for (int mt = 0; mt < 2; mt++)
    #pragma unroll
    for (int nt = 0; nt < 2; nt++) aS[mt][nt] = (f32x4){0.f,0.f,0.f,0.f};
  #pragma unroll
  for (int kk = 0; kk < 2; kk++){
    #pragma unroll
    for (int nt = 0; nt < 2; nt++){
      int ur = nt*16 + l15;
      s16x8 byh = *(const s16x8*)&w2[ur*72 + kk*32 + l4*8];
      s16x8 byl = *(const s16x8*)&w2[2304 + ur*64 + ((((kk*4+l4)) ^ (ur&7))<<3)];
      #pragma unroll
      for (int mt = 0; mt < 2; mt++){
        aS[mt][nt] = mfma16(hfh[mt][kk], byh, aS[mt][nt]);
        aS[mt][nt] = mfma16(hfl[mt][kk], byh, aS[mt][nt]);
        aS[mt][nt] = mfma16(hfh[mt][kk], byl, aS[mt][nt]);
      }
    }
  }
  lfence();
  // softmax + g write (hi @w2[0] stride 40, lo @w2[1280])
  {
    float d0 = ws[OFF_C1+128];
    float cu0 = fw1[2304 + l15];
    float cu1 = fw1[2304 + 16 + l15];
    bool m1 = (16 + l15) < 25;
    #pragma unroll
    for (int mt = 0; mt < 2; mt++){
      #pragma unroll
      for (int r = 0; r < 4; r++){
        int v = mt*16 + l4*4 + r;
        float cvv = (v < 25) ? fw1[2336+v] : 0.f;
        float s0 = aS[mt][0][r] + cu0 + cvv + d0;
        float s1 = m1 ? (aS[mt][1][r] + cu1 + cvv + d0) : -1e30f;
        float mx = fmaxf(s0, s1);
        mx = fmaxf(mx, __shfl_xor(mx, 1));
        mx = fmaxf(mx, __shfl_xor(mx, 2));
        mx = fmaxf(mx, __shfl_xor(mx, 4));
        mx = fmaxf(mx, __shfl_xor(mx, 8));
        float e0 = __expf(s0 - mx);
        float e1v = m1 ? __expf(s1 - mx) : 0.f;
        float sm = e0 + e1v;
        sm += __shfl_xor(sm, 1);
        sm += __shfl_xor(sm, 2);
        sm += __shfl_xor(sm, 4);
        sm += __shfl_xor(sm, 8);
        float inv = 1.f/sm;
        float g0 = e0*inv, g1 = e1v*inv;
        ushortT g0h = f2b(g0), g1h = f2b(g1);
        w2[v*40+l15]         = g0h;
        w2[1280+v*40+l15]    = f2b(g0 - b2f(g0h));
        w2[v*40+16+l15]      = g1h;
        w2[1280+v*40+16+l15] = f2b(g1 - b2f(g1h));
      }
    }
  }
  lfence();
  s16x8 gfh[2], gfl[2];
  #pragma unroll
  for (int nt = 0; nt < 2; nt++){
    gfh[nt] = *(const s16x8*)&w2[(nt*16+l15)*40 + l4*8];
    gfl[nt] = *(const s16x8*)&w2[1280 + (nt*16+l15)*40 + l4*8];
  }
  lfence();   // gf reads done before sHB overwrites w2 (WAR)

  // gcn chain (w1 = YT scratch, w2 = sHB stride HBS, 25 rows, masked reloads)
  const float* tmtt = ws + OFF_TMT + t*128;
  gcn_layer<2,1,0,0>(hfh, wf+WF_W1, wf+WF_W1B, sBN, sBN+64, gfh, gfl, w1, w2, tmtt, lane);
  lfence();
  #pragma unroll
  for (int nt = 0; nt < 2; nt++){
    int v = nt*16 + l15;
    int vr = (v < 25) ? v : 0;
    #pragma unroll
    for (int kk = 0; kk < 2; kk++){
      s16x8 tv = *(const s16x8*)&w2[vr*HBS + kk*32 + l4*8];
      s16x8 z = {0,0,0,0,0,0,0,0};
      hfh[nt][kk] = (v < 25) ? tv : z;
    }
  }
  lfence();
  gcn_layer<2,2,0,0>(hfh, wf+WF_W2, wf+WF_W2B, sBN+128, sBN+256, gfh, gfl, w1, w2, tmtt, lane);
  lfence();
  #pragma unroll
  for (int nt = 0; nt < 2; nt++){
    int v = nt*16 + l15;
    int vr = (v < 25) ? v : 0;
    #pragma unroll
    for (int kk = 0; kk < 4; kk++){
      s16x8 tv = *(const s16x8*)&w2[vr*HBS + kk*32 + l4*8];
      s16x8 z = {0,0,0,0,0,0,0,0};
      hfh[nt][kk] = (v < 25) ? tv : z;
    }
  }
  lfence();
  gcn_layer<4,2,1,1>(hfh, wf+WF_W3, wf+WF_W3B, sBN+384, sBN+512, gfh, gfl, w1, w2, tmtt, lane);

  __syncthreads();
  int bb = ic0 >> 6, sg = (ic0 & 63) >> 2;
  for (int i = tid; i < 3200; i += 256){
    int v = i >> 7, co = i & 127;
    float mx =     b2f(W2[0][v*HBS+co]);
    mx = fmaxf(mx, b2f(W2[1][v*HBS+co]));
    mx = fmaxf(mx, b2f(W2[2][v*HBS+co]));
    mx = fmaxf(mx, b2f(W2[3][v*HBS+co]));
    p.poolb[(((size_t)bb*16+sg)*25+v)*128 + co] = f2b(mx);
  }
}

// ---------------- k_lc: fused loc (conv3 + 1x1 + sum_s), wave = (b,v) --------
__global__ __launch_bounds__(256) void k_lc(P p){
  __shared__ ushortT sA[4][2448];
  __shared__ ushortT sO[4][2176];
  __shared__ float sB1[256], sB2[512];
  int tid = threadIdx.x, wave = tid >> 6, lane = tid & 63;
  int l15 = lane & 15, l4 = lane >> 4;
  int tk = blockIdx.x*4 + wave;
  int b = tk / 25, v = tk % 25;
  float* ws = p.ws;
  if (tid < 256) sB1[tid] = ws[OFF_BNL1 + tid];
  for (int i = tid; i < 512; i += 256) sB2[i] = ws[OFF_BNL2 + i];
  __syncthreads();

  ushortT* A = sA[wave];
  ushortT* O = sO[wave];
  for (int i = lane; i < 68; i += 64){
    *(unsigned*)&A[i*2] = 0u;
    *(unsigned*)&A[2312 + i*2] = 0u;
  }
  for (int i = lane; i < 256; i += 64){
    int r = i >> 4, c8 = i & 15;
    *(uint4*)&A[(r+1)*136 + c8*8] =
      *(const uint4*)&p.poolb[((size_t)(b*16+r)*25 + v)*128 + c8*8];
  }
  lfence();
  const ushortT* lw1f = p.wf + WF_LW1;
  const ushortT* lw2f = p.wf + WF_LW2;

  f32x4 a1[8];
  #pragma unroll
  for (int ct = 0; ct < 8; ct++) a1[ct] = (f32x4){0.f,0.f,0.f,0.f};
  #pragma unroll
  for (int d = 0; d < 3; d++){
    #pragma unroll
    for (int kk = 0; kk < 4; kk++){
      s16x8 af = *(const s16x8*)&A[(l15+d)*136 + kk*32 + l4*8];
      #pragma unroll
      for (int ct = 0; ct < 8; ct++){
        s16x8 bf = *(const s16x8*)(lw1f + (size_t)(((d*4+kk)*8+ct)*512 + lane*8));
        a1[ct] = mfma16(af, bf, a1[ct]);
      }
    }
  }
  #pragma unroll
  for (int ct = 0; ct < 8; ct++){
    int co = ct*16 + l15;
    float s1 = sB1[co], o1 = sB1[128+co];
    #pragma unroll
    for (int r = 0; r < 4; r++)
      O[(l4*4+r)*136 + co] = f2b(fmaxf(s1*a1[ct][r] + o1, 0.f));
  }
  lfence();
  s16x8 af2[4];
  #pragma unroll
  for (int kk = 0; kk < 4; kk++)
    af2[kk] = *(const s16x8*)&O[l15*136 + kk*32 + l4*8];
  f32x4 a2[16];
  #pragma unroll
  for (int ct = 0; ct < 16; ct++) a2[ct] = (f32x4){0.f,0.f,0.f,0.f};
  #pragma unroll
  for (int kk = 0; kk < 4; kk++){
    #pragma unroll
    for (int ct = 0; ct < 16; ct++){
      s16x8 bf = *(const s16x8*)(lw2f + (size_t)((kk*16+ct)*512 + lane*8));
      a2[ct] = mfma16(af2[kk], bf, a2[ct]);
    }
  }
  #pragma unroll
  for (int ct = 0; ct < 16; ct++){
    int co = ct*16 + l15;
    float s2 = sB2[co], o2 = sB2[256+co];
    float sum = 0.f;
    #pragma unroll
    for (int r = 0; r < 4; r++) sum += fmaxf(s2*a2[ct][r] + o2, 0.f);
    sum += __shfl_xor(sum, 16);
    sum += __shfl_xor(sum, 32);
    if (lane < 16) ws[OFF_PART2 + (size_t)(b*25+v)*256 + co] = sum;
  }
}

// ---------------- k_fc: pool (inline) + FC heads, 1408 blocks ----------------
__global__ __launch_bounds__(256) void k_fc(P p){
  __shared__ float sp[5*257];
  int tid = threadIdx.x;
  int n = blockIdx.x & 127, ch = blockIdx.x >> 7;
  const float* part = p.ws + OFF_PART2;
  float tot = 0.f, hd = 0.f, hn = 0.f, ft = 0.f, hq = 0.f;
  for (int m2 = 0; m2 < 2; m2++){
    for (int v = 0; v < 25; v++){
      float pv = part[(size_t)((n*2+m2)*25+v)*256 + tid];
      tot += pv;
      unsigned bit = 1u << v;
      if (bit & 0x10000Cu)  hd += pv;
      if (bit & 0x1E00FF0u) hn += pv;
      if (bit & 0xFF000u)   ft += pv;
      if (bit & 0x11007u)   hq += pv;
    }
  }
  sp[tid]         = tot * (1.f/800.f);
  sp[257+tid]     = hd  * (1.f/96.f);
  sp[2*257+tid]   = hn  * (1.f/384.f);
  sp[3*257+tid]   = ft  * (1.f/256.f);
  sp[4*257+tid]   = hq  * (1.f/160.f);
  __syncthreads();
  int o = ch*256 + tid;
  if (o < 2620){
    int sel, off;
    if (o < 60)        { sel = 0; off = n*60+o; }
    else if (o < 572)  { sel = 0; off = 7680   + n*512+(o-60); }
    else if (o < 1084) { sel = 1; off = 73221  + n*512+(o-572); }
    else if (o < 1596) { sel = 2; off = 138757 + n*512+(o-1084); }
    else if (o < 2108) { sel = 4; off = 204293 + n*512+(o-1596); }
    else               { sel = 3; off = 269829 + n*512+(o-2108); }
    const float* pl = sp + sel*257;
    const float* wo = p.ws + OFF_WT + o;
    float acc = p.ws[OFF_FB + o];
    #pragma unroll 8
    for (int c = 0; c < 256; c++) acc += wo[(size_t)c*2624] * pl[c];
    p.out[off] = acc;
  }
  if (blockIdx.x == 0 && tid < 5) p.out[73216+tid] = p.ls[tid];
}

extern "C" void kernel_launch(void* const* d_in, const int* in_sizes, int n_in,
                              void* d_out, int out_size, void* d_ws, size_t ws_size,
                              hipStream_t stream){
  P p;
  p.x        = (const float*)d_in[0];
  p.bn_joint = (const float*)d_in[1];
  p.jw1      = (const float*)d_in[2];
  p.jb1      = (const float*)d_in[3];
  p.jw2      = (const float*)d_in[4];
  p.jb2      = (const float*)d_in[5];
  p.bn_dif   = (const float*)d_in[6];
  p.dw1      = (const float*)d_in[7];
  p.db1      = (const float*)d_in[8];
  p.dw2      = (const float*)d_in[9];
  p.db2      = (const float*)d_in[10];
  p.tw1      = (const float*)d_in[11];
  p.tb1      = (const float*)d_in[12];
  p.tw2      = (const float*)d_in[13];
  p.tb2      = (const float*)d_in[14];
  p.sw1      = (const float*)d_in[15];
  p.sb1      = (const float*)d_in[16];
  p.sw2      = (const float*)d_in[17];
  p.sb2      = (const float*)d_in[18];
  p.g1w      = (const float*)d_in[19];
  p.g1b      = (const float*)d_in[20];
  p.g2w      = (const float*)d_in[21];
  p.g2b      = (const float*)d_in[22];
  p.c1w      = (const float*)d_in[23];
  p.c1w1     = (const float*)d_in[24];
  p.c1b1     = (const float*)d_in[25];
  p.bnc1     = (const float*)d_in[26];
  p.c2w      = (const float*)d_in[27];
  p.c2w1     = (const float*)d_in[28];
  p.c2b1     = (const float*)d_in[29];
  p.bnc2     = (const float*)d_in[30];
  p.c3w      = (const float*)d_in[31];
  p.c3w1     = (const float*)d_in[32];
  p.c3b1     = (const float*)d_in[33];
  p.bnc3     = (const float*)d_in[34];
  p.lw1      = (const float*)d_in[35];
  p.lb1      = (const float*)d_in[36];
  p.bnl1     = (const float*)d_in[37];
  p.lw2      = (const float*)d_in[38];
  p.lb2      = (const float*)d_in[39];
  p.bnl2     = (const float*)d_in[40];
  p.fcw      = (const float*)d_in[41];
  p.fcb      = (const float*)d_in[42];
  p.hww      = (const float*)d_in[43];
  p.hwb      = (const float*)d_in[44];
  p.pw       = (const float*)d_in[45];
  p.pb       = (const float*)d_in[46];
  p.ls       = (const float*)d_in[47];
  p.ws  = (float*)d_ws;
  p.out = (float*)d_out;

  char* wsb = (char*)d_ws;
  p.wf    = (const ushortT*)(wsb + WF_B);
  p.poolb = (ushortT*)(wsb + POOL_B);

  k_pre1 <<<dim3(32),   dim3(256), 0, stream>>>(p);
  k_pre2 <<<dim3(32),   dim3(256), 0, stream>>>(p);
  k_fwd  <<<dim3(4096), dim3(256), 0, stream>>>(p);
  k_lc   <<<dim3(1600), dim3(256), 0, stream>>>(p);
  k_fc   <<<dim3(1408), dim3(256), 0, stream>>>(p);
}